// Round 3
// baseline (10100.217 us; speedup 1.0000x reference)
//
#include <hip/hip_runtime.h>
#include <hip/hip_bf16.h>
#include <hip/hip_cooperative_groups.h>

namespace cg = cooperative_groups;

typedef __attribute__((ext_vector_type(8))) short short8;
typedef __attribute__((ext_vector_type(4))) float floatx4;

#define NB 128      // batch N
#define LS 64       // seq L
#define HD 512      // hidden H
#define ED 512      // embed E
#define NH 65536    // NB*HD elements per s-slab
#define LDA 72      // LDS tile stride (64 + 8 pad, keeps 16B alignment)

// ws layout (byte offsets)
#define OFF_WIN    0ull          // W_in bf16   [512*512]
#define OFF_WSANI  524288ull     // W_sani bf16 [512*1024]
#define OFF_WOUT   1572864ull    // W_out bf16  [512*512]
#define OFF_XT     2097152ull    // x_t bf16    [64][128][512]   (= level 0)
#define OFF_LVL0   10485760ull   // level ping  bf16 [64][128][512]
#define OFF_LVL1   18874368ull   // level pong  bf16 [64][128][512]
#define OFF_OUTS   27262976ull   // outs bf16   [64][128][512]
#define OFF_PART   35651584ull   // partials f32 [128]
#define OFF_Y      OFF_LVL0      // Y f32 [8192][512] aliases dead lvl bufs after recurrence

static __device__ __forceinline__ unsigned short f2b(float f) {
  unsigned u = __float_as_uint(f);
  u += 0x7fffu + ((u >> 16) & 1u);   // round-to-nearest-even
  return (unsigned short)(u >> 16);
}

// ---- shared GEMM pieces: BM=64, BN=128, BK=64, 256 threads (4 waves, 2x2) ----

__device__ __forceinline__ void gemm_core24(const unsigned short* As, const unsigned short* Bs,
                                            floatx4 acc[2][4], int wm, int wn, int lane) {
  const int rb = lane & 15;
  const int kg = (lane >> 4) * 8;
#pragma unroll
  for (int kk = 0; kk < 64; kk += 32) {
    short8 a[2], b[4];
#pragma unroll
    for (int i = 0; i < 2; ++i)
      a[i] = *(const short8*)&As[(wm * 32 + i * 16 + rb) * LDA + kk + kg];
#pragma unroll
    for (int j = 0; j < 4; ++j)
      b[j] = *(const short8*)&Bs[(wn * 64 + j * 16 + rb) * LDA + kk + kg];
#pragma unroll
    for (int i = 0; i < 2; ++i)
#pragma unroll
      for (int j = 0; j < 4; ++j)
        acc[i][j] = __builtin_amdgcn_mfma_f32_16x16x32_bf16(a[i], b[j], acc[i][j], 0, 0, 0);
  }
}

// A tile: 64 rows x 64 cols, bf16 source with row stride 512
__device__ __forceinline__ void stageA_bf16(unsigned short* As, const unsigned short* src, int tid) {
  int r = tid >> 3, kc = (tid & 7) * 8;
#pragma unroll
  for (int p = 0; p < 2; ++p)
    *(uint4*)&As[(r + p * 32) * LDA + kc] = *(const uint4*)(src + (size_t)(r + p * 32) * 512 + kc);
}

// A tile via embedding gather (fp32 table -> bf16)
__device__ __forceinline__ void stageA_emb(unsigned short* As, const float* table,
                                           const int* labels, int m0, int k0, int tid) {
  int r = tid >> 3, kc = (tid & 7) * 8;
#pragma unroll
  for (int p = 0; p < 2; ++p) {
    int row = r + p * 32;
    const float* s = table + (size_t)labels[m0 + row] * ED + k0 + kc;
    floatx4 f0 = *(const floatx4*)s;
    floatx4 f1 = *(const floatx4*)(s + 4);
    uint4 u;
    u.x = (unsigned)f2b(f0.x) | ((unsigned)f2b(f0.y) << 16);
    u.y = (unsigned)f2b(f0.z) | ((unsigned)f2b(f0.w) << 16);
    u.z = (unsigned)f2b(f1.x) | ((unsigned)f2b(f1.y) << 16);
    u.w = (unsigned)f2b(f1.z) | ((unsigned)f2b(f1.w) << 16);
    *(uint4*)&As[row * LDA + kc] = u;
  }
}

// B tile: 128 rows (of B^T) x 64 cols, bf16, row stride ldB
__device__ __forceinline__ void stageB(unsigned short* Bs, const unsigned short* src, int ldB, int tid) {
  int r = tid >> 3, kc = (tid & 7) * 8;
#pragma unroll
  for (int p = 0; p < 4; ++p)
    *(uint4*)&Bs[(r + p * 32) * LDA + kc] = *(const uint4*)(src + (size_t)(r + p * 32) * ldB + kc);
}

// ---- phase 1: x_t[l][n][h] = bf16( emb(labels) @ W_in^T + b_in ) ----
__global__ __launch_bounds__(256) void k_gemm_emb(const float* __restrict__ table,
                                                  const int* __restrict__ labels,
                                                  const unsigned short* __restrict__ Wb,
                                                  const float* __restrict__ bias,
                                                  unsigned short* __restrict__ xt) {
  __shared__ unsigned short As[64 * LDA];
  __shared__ unsigned short Bs[128 * LDA];
  int tid = threadIdx.x;
  int mtile = blockIdx.x >> 2, ntile = blockIdx.x & 3;
  int m0 = mtile * 64, n0 = ntile * 128;
  int lane = tid & 63, wave = tid >> 6, wm = wave >> 1, wn = wave & 1;
  floatx4 acc[2][4] = {};
  for (int k0 = 0; k0 < 512; k0 += 64) {
    stageA_emb(As, table, labels, m0, k0, tid);
    stageB(Bs, Wb + (size_t)n0 * 512 + k0, 512, tid);
    __syncthreads();
    gemm_core24(As, Bs, acc, wm, wn, lane);
    __syncthreads();
  }
  int rb = lane & 15, rg = (lane >> 4) * 4;
#pragma unroll
  for (int i = 0; i < 2; ++i)
#pragma unroll
    for (int j = 0; j < 4; ++j) {
      int col = n0 + wn * 64 + j * 16 + rb;
      float bv = bias[col];
#pragma unroll
      for (int reg = 0; reg < 4; ++reg) {
        int m = m0 + wm * 32 + i * 16 + rg + reg;
        int n = m >> 6, l = m & 63;
        xt[((size_t)l * NB + n) * HD + col] = f2b(acc[i][j][reg] + bv);
      }
    }
}

// ---- phase 2 (persistent, cooperative): all 63 levels with grid.sync between.
//      Level li: h(s,li) = h(s-1,li-1)@W1^T + h(s,li-1)@W2^T + b  for s in [li,63].
//      504 blocks; level li uses blocks [0, 8*(64-li)); 1 tile/block/level.
//      K-loop is reg-prefetch pipelined (load k+1 while MFMA consumes k). ----
__global__ __launch_bounds__(256) void k_recur(const unsigned short* __restrict__ xt,
                                               unsigned short* __restrict__ lvl0,
                                               unsigned short* __restrict__ lvl1,
                                               unsigned short* __restrict__ outs,
                                               const unsigned short* __restrict__ Wsani,
                                               const float* __restrict__ bias) {
  cg::grid_group grid = cg::this_grid();
  __shared__ unsigned short As[64 * LDA];
  __shared__ unsigned short Bs[128 * LDA];
  const int tid = threadIdx.x;
  const int bid = blockIdx.x;
  const int lane = tid & 63, wave = tid >> 6, wm = wave >> 1, wn = wave & 1;
  const int r = tid >> 3, kc = (tid & 7) * 8;

  for (int li = 1; li <= 63; ++li) {
    const int ntile = 8 * (64 - li);
    if (bid < ntile) {
      const unsigned short* src = (li == 1) ? xt : ((li & 1) ? lvl0 : lvl1);
      unsigned short* dstbuf = (li & 1) ? lvl1 : lvl0;
      const int mtile = bid >> 2, n0 = (bid & 3) * 128;
      const int s = li + (mtile >> 1);        // each 64-row tile lies in one s-slab
      const int nb0 = (mtile & 1) * 64;       // row offset within slab
      const unsigned short* own  = src + (size_t)s * NH + (size_t)nb0 * HD;  // h(s, li-1)
      const unsigned short* diag = own - NH;                                  // h(s-1, li-1)
      unsigned short* d = dstbuf + (size_t)s * NH + (size_t)nb0 * HD;

      floatx4 acc[2][4] = {};
      uint4 ra[2], rb4[4];
      // prologue: load K-step 0 (k0=0 -> diag / W1 half)
      ra[0] = *(const uint4*)(diag + (size_t)r * HD + kc);
      ra[1] = *(const uint4*)(diag + (size_t)(r + 32) * HD + kc);
#pragma unroll
      for (int p = 0; p < 4; ++p)
        rb4[p] = *(const uint4*)(Wsani + (size_t)(n0 + r + p * 32) * 1024 + kc);

      for (int k = 0; k < 16; ++k) {
        __syncthreads();                       // prior step's LDS reads done
        *(uint4*)&As[r * LDA + kc] = ra[0];
        *(uint4*)&As[(r + 32) * LDA + kc] = ra[1];
#pragma unroll
        for (int p = 0; p < 4; ++p)
          *(uint4*)&Bs[(r + p * 32) * LDA + kc] = rb4[p];
        __syncthreads();
        if (k < 15) {                          // prefetch next step into regs
          const int k0 = (k + 1) * 64;
          const unsigned short* a0 = (k0 < 512) ? (diag + k0) : (own + (k0 - 512));
          ra[0] = *(const uint4*)(a0 + (size_t)r * HD + kc);
          ra[1] = *(const uint4*)(a0 + (size_t)(r + 32) * HD + kc);
#pragma unroll
          for (int p = 0; p < 4; ++p)
            rb4[p] = *(const uint4*)(Wsani + (size_t)(n0 + r + p * 32) * 1024 + k0 + kc);
        }
        gemm_core24(As, Bs, acc, wm, wn, lane);  // loads fly under MFMA
      }

      const int rb = lane & 15, rg = (lane >> 4) * 4;
      const bool isout = (s == li);            // outs[li] = h(li, li)
      unsigned short* d2 = outs + (size_t)li * NH + (size_t)nb0 * HD;
#pragma unroll
      for (int i = 0; i < 2; ++i)
#pragma unroll
        for (int j = 0; j < 4; ++j) {
          int col = n0 + wn * 64 + j * 16 + rb;
          float bv = bias[col];
#pragma unroll
          for (int reg = 0; reg < 4; ++reg) {
            int row = wm * 32 + i * 16 + rg + reg;
            unsigned short v = f2b(acc[i][j][reg] + bv);
            d[(size_t)row * HD + col] = v;
            if (isout) d2[(size_t)row * HD + col] = v;
          }
        }
    }
    __threadfence();   // agent-scope release of this level's writes
    grid.sync();       // all levels' consumers start after producers (acquire)
  }
}

// ---- phase 3: Y = outs_flat @ W_out^T + b_out  (fp32 out) ----
__global__ __launch_bounds__(256) void k_gemm_out(const unsigned short* __restrict__ outs,
                                                  const unsigned short* __restrict__ Wb,
                                                  const float* __restrict__ bias,
                                                  float* __restrict__ Y) {
  __shared__ unsigned short As[64 * LDA];
  __shared__ unsigned short Bs[128 * LDA];
  int tid = threadIdx.x;
  int mtile = blockIdx.x >> 2, ntile = blockIdx.x & 3;
  int m0 = mtile * 64, n0 = ntile * 128;
  int lane = tid & 63, wave = tid >> 6, wm = wave >> 1, wn = wave & 1;
  floatx4 acc[2][4] = {};
  for (int k0 = 0; k0 < 512; k0 += 64) {
    stageA_bf16(As, outs + (size_t)m0 * 512 + k0, tid);
    stageB(Bs, Wb + (size_t)n0 * 512 + k0, 512, tid);
    __syncthreads();
    gemm_core24(As, Bs, acc, wm, wn, lane);
    __syncthreads();
  }
  int rb = lane & 15, rg = (lane >> 4) * 4;
#pragma unroll
  for (int i = 0; i < 2; ++i)
#pragma unroll
    for (int j = 0; j < 4; ++j) {
      int col = n0 + wn * 64 + j * 16 + rb;
      float bv = bias[col];
#pragma unroll
      for (int reg = 0; reg < 4; ++reg) {
        int row = m0 + wm * 32 + i * 16 + rg + reg;
        Y[(size_t)row * 512 + col] = acc[i][j][reg] + bv;
      }
    }
}

// ---- weights fp32 -> bf16 (one float4 per thread over concat regions) ----
__global__ __launch_bounds__(256) void k_cvtw(const float* __restrict__ Win,
                                              const float* __restrict__ Wsani,
                                              const float* __restrict__ Wout,
                                              unsigned short* __restrict__ dWin,
                                              unsigned short* __restrict__ dWsani,
                                              unsigned short* __restrict__ dWout) {
  int i = blockIdx.x * 256 + threadIdx.x;  // float4 index, total 262144
  const float* src;
  unsigned short* dst;
  int off;
  if (i < 65536)       { src = Win;   dst = dWin;   off = i; }
  else if (i < 196608) { src = Wsani; dst = dWsani; off = i - 65536; }
  else                 { src = Wout;  dst = dWout;  off = i - 196608; }
  floatx4 v = *(const floatx4*)(src + (size_t)off * 4);
  uint2 u;
  u.x = (unsigned)f2b(v.x) | ((unsigned)f2b(v.y) << 16);
  u.y = (unsigned)f2b(v.z) | ((unsigned)f2b(v.w) << 16);
  *(uint2*)(dst + (size_t)off * 4) = u;
}

__global__ void k_copy(const uint4* __restrict__ src, uint4* __restrict__ dst, int n) {
  int i = blockIdx.x * 256 + threadIdx.x;
  if (i < n) dst[i] = src[i];
}

// ---- loss: per n, column-softmax over 64 consecutive Y rows, dot with emb ----
__global__ __launch_bounds__(256) void k_loss(const float* __restrict__ Y,
                                              const float* __restrict__ table,
                                              const int* __restrict__ labels,
                                              float* __restrict__ partials) {
  int n = blockIdx.x, tid = threadIdx.x;
  float total = 0.f;
#pragma unroll
  for (int e2 = 0; e2 < 2; ++e2) {
    int e = e2 * 256 + tid;
    float mx = -1e30f;
    for (int l = 0; l < 64; ++l)
      mx = fmaxf(mx, Y[(size_t)(n * 64 + l) * 512 + e]);
    float se = 0.f;
    for (int l = 0; l < 64; ++l)
      se += expf(Y[(size_t)(n * 64 + l) * 512 + e] - mx);
    float lse = mx + logf(se);
    for (int l = 0; l < 64; ++l) {
      float embv = table[(size_t)labels[n * 64 + l] * ED + e];
      total += embv * (Y[(size_t)(n * 64 + l) * 512 + e] - lse);
    }
  }
  __shared__ float red[256];
  red[tid] = total;
  __syncthreads();
  for (int s2 = 128; s2 > 0; s2 >>= 1) {
    if (tid < s2) red[tid] += red[tid + s2];
    __syncthreads();
  }
  if (tid == 0) partials[n] = red[0];
}

__global__ void k_final(const float* __restrict__ partials, float* __restrict__ out) {
  if (threadIdx.x == 0) {
    double s = 0.0;
    for (int i = 0; i < 128; ++i) s += (double)partials[i];
    out[0] = (float)(-s / 65536.0);
  }
}

extern "C" void kernel_launch(void* const* d_in, const int* in_sizes, int n_in,
                              void* d_out, int out_size, void* d_ws, size_t ws_size,
                              hipStream_t stream) {
  const int*   labels = (const int*)d_in[0];
  const float* table  = (const float*)d_in[1];
  const float* W_in   = (const float*)d_in[2];
  const float* b_in   = (const float*)d_in[3];
  const float* W_sani = (const float*)d_in[4];
  const float* b_sani = (const float*)d_in[5];
  const float* W_out  = (const float*)d_in[6];
  const float* b_out  = (const float*)d_in[7];

  char* ws = (char*)d_ws;
  unsigned short* Win_b   = (unsigned short*)(ws + OFF_WIN);
  unsigned short* Wsani_b = (unsigned short*)(ws + OFF_WSANI);
  unsigned short* Wout_b  = (unsigned short*)(ws + OFF_WOUT);
  unsigned short* xt      = (unsigned short*)(ws + OFF_XT);
  unsigned short* lvl0    = (unsigned short*)(ws + OFF_LVL0);
  unsigned short* lvl1    = (unsigned short*)(ws + OFF_LVL1);
  unsigned short* outs    = (unsigned short*)(ws + OFF_OUTS);
  float*          parts   = (float*)(ws + OFF_PART);
  float*          Y       = (float*)(ws + OFF_Y);

  k_cvtw<<<1024, 256, 0, stream>>>(W_in, W_sani, W_out, Win_b, Wsani_b, Wout_b);
  k_gemm_emb<<<512, 256, 0, stream>>>(table, labels, Win_b, b_in, xt);
  k_copy<<<32, 256, 0, stream>>>((const uint4*)xt, (uint4*)outs, 8192);  // outs[0] = x_t[0]

  {
    const unsigned short* xt_c = xt;
    const unsigned short* Ws_c = Wsani_b;
    const float* bs_c = b_sani;
    void* args[] = { (void*)&xt_c, (void*)&lvl0, (void*)&lvl1, (void*)&outs,
                     (void*)&Ws_c, (void*)&bs_c };
    hipLaunchCooperativeKernel((const void*)k_recur, dim3(504), dim3(256),
                               args, 0, stream);
  }

  k_gemm_out<<<512, 256, 0, stream>>>(outs, Wout_b, b_out, Y);
  k_loss<<<128, 256, 0, stream>>>(Y, table, labels, parts);
  k_final<<<1, 64, 0, stream>>>(parts, (float*)d_out);
}

// Round 4
// 2001.718 us; speedup vs baseline: 5.0458x; 5.0458x over previous
//
#include <hip/hip_runtime.h>
#include <hip/hip_bf16.h>

typedef __attribute__((ext_vector_type(8))) short short8;
typedef __attribute__((ext_vector_type(4))) float floatx4;

#define NB 128      // batch N
#define LS 64       // seq L
#define HD 512      // hidden H
#define ED 512      // embed E
#define NH 65536    // NB*HD elements per s-slab
#define LDA 72      // LDS tile stride (64 + 8 pad, keeps 16B alignment)

// ws layout (byte offsets)
#define OFF_WIN    0ull          // W_in bf16   [512*512]
#define OFF_WOUT   524288ull     // W_out bf16  [512*512]
#define OFF_XT     1048576ull    // x_t bf16    [64][128][512]  (= level 0)
#define OFF_LVL0   9437184ull    // level ping  bf16 [64][128][512]
#define OFF_LVL1   17825792ull   // level pong  bf16 [64][128][512]
#define OFF_OUTS   26214400ull   // outs bf16   [64][128][512]
#define OFF_PA     34603008ull   // coef chain ping f32 (up to 5x 512x512)
#define OFF_PB     39845888ull   // coef chain pong f32
#define OFF_BCAT   45088768ull   // Bcat_1..4 bf16 concat (7 MB)
#define OFF_BETA   52428800ull   // beta_1..4 f32 [4][512]
#define OFF_PART   52436992ull   // partials f32 [128]
#define OFF_Y      OFF_LVL0      // Y f32 [8192][512] aliases lvl bufs after recurrence

static __device__ __forceinline__ unsigned short f2b(float f) {
  unsigned u = __float_as_uint(f);
  u += 0x7fffu + ((u >> 16) & 1u);   // round-to-nearest-even
  return (unsigned short)(u >> 16);
}
static __device__ __forceinline__ float b2f(unsigned short h) {
  return __uint_as_float(((unsigned)h) << 16);
}

// load 8 consecutive f32, produce bf16x8 packed; variant 0 = hi, 1 = lo residual
static __device__ __forceinline__ uint4 cvt8(const float* s, int variant) {
  floatx4 f0 = *(const floatx4*)s;
  floatx4 f1 = *(const floatx4*)(s + 4);
  float f[8] = {f0.x, f0.y, f0.z, f0.w, f1.x, f1.y, f1.z, f1.w};
  unsigned short b[8];
#pragma unroll
  for (int k = 0; k < 8; ++k) {
    unsigned short h = f2b(f[k]);
    b[k] = (variant == 0) ? h : f2b(f[k] - b2f(h));
  }
  uint4 u;
  u.x = b[0] | ((unsigned)b[1] << 16); u.y = b[2] | ((unsigned)b[3] << 16);
  u.z = b[4] | ((unsigned)b[5] << 16); u.w = b[6] | ((unsigned)b[7] << 16);
  return u;
}

// ---- shared GEMM core: BM=64, BN=128, BK=64, 256 threads (4 waves, 2x2) ----
__device__ __forceinline__ void gemm_core24(const unsigned short* As, const unsigned short* Bs,
                                            floatx4 acc[2][4], int wm, int wn, int lane) {
  const int rb = lane & 15;
  const int kg = (lane >> 4) * 8;
#pragma unroll
  for (int kk = 0; kk < 64; kk += 32) {
    short8 a[2], b[4];
#pragma unroll
    for (int i = 0; i < 2; ++i)
      a[i] = *(const short8*)&As[(wm * 32 + i * 16 + rb) * LDA + kk + kg];
#pragma unroll
    for (int j = 0; j < 4; ++j)
      b[j] = *(const short8*)&Bs[(wn * 64 + j * 16 + rb) * LDA + kk + kg];
#pragma unroll
    for (int i = 0; i < 2; ++i)
#pragma unroll
      for (int j = 0; j < 4; ++j)
        acc[i][j] = __builtin_amdgcn_mfma_f32_16x16x32_bf16(a[i], b[j], acc[i][j], 0, 0, 0);
  }
}

__device__ __forceinline__ void stageA_bf16(unsigned short* As, const unsigned short* src, int tid) {
  int r = tid >> 3, kc = (tid & 7) * 8;
#pragma unroll
  for (int p = 0; p < 2; ++p)
    *(uint4*)&As[(r + p * 32) * LDA + kc] = *(const uint4*)(src + (size_t)(r + p * 32) * 512 + kc);
}

__device__ __forceinline__ void stageA_emb(unsigned short* As, const float* table,
                                           const int* labels, int m0, int k0, int tid) {
  int r = tid >> 3, kc = (tid & 7) * 8;
#pragma unroll
  for (int p = 0; p < 2; ++p) {
    int row = r + p * 32;
    const float* s = table + (size_t)labels[m0 + row] * ED + k0 + kc;
    *(uint4*)&As[row * LDA + kc] = cvt8(s, 0);
  }
}

__device__ __forceinline__ void stageB(unsigned short* Bs, const unsigned short* src, int ldB, int tid) {
  int r = tid >> 3, kc = (tid & 7) * 8;
#pragma unroll
  for (int p = 0; p < 4; ++p)
    *(uint4*)&Bs[(r + p * 32) * LDA + kc] = *(const uint4*)(src + (size_t)(r + p * 32) * ldB + kc);
}

// ---- phase 1: x_t[l][n][h] = bf16( emb(labels) @ W_in^T + b_in ) ----
__global__ __launch_bounds__(256) void k_gemm_emb(const float* __restrict__ table,
                                                  const int* __restrict__ labels,
                                                  const unsigned short* __restrict__ Wb,
                                                  const float* __restrict__ bias,
                                                  unsigned short* __restrict__ xt) {
  __shared__ unsigned short As[64 * LDA];
  __shared__ unsigned short Bs[128 * LDA];
  int tid = threadIdx.x;
  int mtile = blockIdx.x >> 2, ntile = blockIdx.x & 3;
  int m0 = mtile * 64, n0 = ntile * 128;
  int lane = tid & 63, wave = tid >> 6, wm = wave >> 1, wn = wave & 1;
  floatx4 acc[2][4] = {};
  for (int k0 = 0; k0 < 512; k0 += 64) {
    stageA_emb(As, table, labels, m0, k0, tid);
    stageB(Bs, Wb + (size_t)n0 * 512 + k0, 512, tid);
    __syncthreads();
    gemm_core24(As, Bs, acc, wm, wn, lane);
    __syncthreads();
  }
  int rb = lane & 15, rg = (lane >> 4) * 4;
#pragma unroll
  for (int i = 0; i < 2; ++i)
#pragma unroll
    for (int j = 0; j < 4; ++j) {
      int col = n0 + wn * 64 + j * 16 + rb;
      float bv = bias[col];
#pragma unroll
      for (int reg = 0; reg < 4; ++reg) {
        int m = m0 + wm * 32 + i * 16 + rg + reg;
        int n = m >> 6, l = m & 63;
        xt[((size_t)l * NB + n) * HD + col] = f2b(acc[i][j][reg] + bv);
      }
    }
}

// ---- coefficient chain iteration: P_{m+1,j} = gemm(P_{m,j}, W2) + gemm(P_{m,j-1}, W1)
//      P stored transposed ([k][t] row-major, P = A^T). hi/lo split (3 terms) for ~f32 accuracy. ----
__global__ __launch_bounds__(256) void k_coef(const float* __restrict__ Pin,
                                              float* __restrict__ Pout,
                                              const float* __restrict__ Ws,
                                              int m) {
  __shared__ unsigned short As[64 * LDA];
  __shared__ unsigned short Bs[128 * LDA];
  int tid = threadIdx.x;
  int j = blockIdx.x >> 5, tile = blockIdx.x & 31;
  int k0r = (tile >> 2) * 64, n0 = (tile & 3) * 128;
  int lane = tid & 63, wave = tid >> 6, wm = wave >> 1, wn = wave & 1;
  int r_ = tid >> 3, kc = (tid & 7) * 8;
  floatx4 acc[2][4] = {};
  for (int term = 0; term < 2; ++term) {
    if (term == 0 && j > m) continue;
    if (term == 1 && j < 1) continue;
    const float* Psrc = Pin + (size_t)(term == 0 ? j : j - 1) * 262144;
    const int coloff = (term == 0) ? 512 : 0;   // term0: W2, term1: W1
    for (int v = 0; v < 3; ++v) {                // (hi,hi),(hi,lo),(lo,hi)
      int va = (v == 2) ? 1 : 0;
      int vb = (v == 1) ? 1 : 0;
      for (int t0 = 0; t0 < 512; t0 += 64) {
#pragma unroll
        for (int p = 0; p < 2; ++p) {
          int row = r_ + p * 32;
          *(uint4*)&As[row * LDA + kc] = cvt8(Psrc + (size_t)(k0r + row) * 512 + t0 + kc, va);
        }
#pragma unroll
        for (int p = 0; p < 4; ++p) {
          int row = r_ + p * 32;
          *(uint4*)&Bs[row * LDA + kc] = cvt8(Ws + (size_t)(n0 + row) * 1024 + coloff + t0 + kc, vb);
        }
        __syncthreads();
        gemm_core24(As, Bs, acc, wm, wn, lane);
        __syncthreads();
      }
    }
  }
  int rb = lane & 15, rg = (lane >> 4) * 4;
#pragma unroll
  for (int i = 0; i < 2; ++i)
#pragma unroll
    for (int jj = 0; jj < 4; ++jj) {
      int col = n0 + wn * 64 + jj * 16 + rb;
#pragma unroll
      for (int reg = 0; reg < 4; ++reg) {
        int row = wm * 32 + i * 16 + rg + reg;
        Pout[(size_t)j * 262144 + (size_t)(k0r + row) * 512 + col] = acc[i][jj][reg];
      }
    }
}

// ---- P_1 = {W2^T, W1^T} f32 (transpose of W_sani halves) ----
__global__ __launch_bounds__(256) void k_trW(const float* __restrict__ Ws,
                                             float* __restrict__ P1) {
  __shared__ float t[64][65];
  int mat = blockIdx.x >> 6, tile = blockIdx.x & 63;
  int a0 = (tile >> 3) * 64, b0 = (tile & 7) * 64;
  int coloff = (mat == 0) ? 512 : 0;   // P_{1,0}=W2^T, P_{1,1}=W1^T
  for (int pp = 0; pp < 16; ++pp) {
    int idx = pp * 256 + threadIdx.x, rr = idx >> 6, cc = idx & 63;
    t[rr][cc] = Ws[(size_t)(b0 + rr) * 1024 + coloff + a0 + cc];
  }
  __syncthreads();
  for (int pp = 0; pp < 16; ++pp) {
    int idx = pp * 256 + threadIdx.x, rr = idx >> 6, cc = idx & 63;
    P1[(size_t)mat * 262144 + (size_t)(a0 + rr) * 512 + b0 + cc] = t[cc][rr];
  }
}

// ---- Bcat_r[i][q*512+t] = A_{r,r-q}[i][t] = P_{r,r-q}[t][i], f32 -> bf16 ----
__global__ __launch_bounds__(256) void k_trB(const float* __restrict__ Pr,
                                             unsigned short* __restrict__ Bout,
                                             int r) {
  __shared__ float t[64][65];
  int q = blockIdx.x >> 6, tile = blockIdx.x & 63;
  int t0 = (tile >> 3) * 64, i0 = (tile & 7) * 64;
  const float* P = Pr + (size_t)(r - q) * 262144;
  int ldB = (r + 1) * 512;
  for (int pp = 0; pp < 16; ++pp) {
    int idx = pp * 256 + threadIdx.x, rr = idx >> 6, cc = idx & 63;
    t[rr][cc] = P[(size_t)(t0 + rr) * 512 + i0 + cc];
  }
  __syncthreads();
  for (int pp = 0; pp < 16; ++pp) {
    int idx = pp * 256 + threadIdx.x, rr = idx >> 6, cc = idx & 63;
    Bout[(size_t)(i0 + rr) * ldB + q * 512 + t0 + cc] = f2b(t[cc][rr]);
  }
}

// ---- beta_{r+1}[i] = sum_k (W1+W2)[i][k] * beta_r[k] + b[i] ----
__global__ __launch_bounds__(64) void k_bias_step(const float* __restrict__ Ws,
                                                  const float* __restrict__ b,
                                                  const float* __restrict__ bprev,
                                                  float* __restrict__ bout) {
  int i = blockIdx.x, t = threadIdx.x;
  float p = 0.f;
  for (int k = t; k < 512; k += 64)
    p += (Ws[(size_t)i * 1024 + k] + Ws[(size_t)i * 1024 + 512 + k]) * bprev[k];
#pragma unroll
  for (int off = 32; off > 0; off >>= 1) p += __shfl_down(p, off, 64);
  if (t == 0) bout[i] = p + b[i];
}

// ---- phase 2: one multi-level step. main: h(s,L+m) for s in [L+m,63], K=(m+1)*512;
//      diag blocks: outs[L+r] = h(L+r, L+r) via A_r, r=1..m-1. Reg-prefetch pipelined. ----
__global__ __launch_bounds__(256) void k_step(const unsigned short* __restrict__ src,
                                              unsigned short* __restrict__ dst,
                                              unsigned short* __restrict__ outs,
                                              const unsigned short* __restrict__ Bcat,
                                              const float* __restrict__ beta,
                                              int L_prev, int m, int nmain) {
  __shared__ unsigned short As[64 * LDA];
  __shared__ unsigned short Bs[128 * LDA];
  const int tid = threadIdx.x, bid = blockIdx.x;
  const int mainWG = nmain * 8;
  int r, s;
  if (bid < mainWG) { r = m; s = L_prev + m + (bid >> 3); }
  else              { r = 1 + ((bid - mainWG) >> 3); s = L_prev + r; }
  const int sub = bid & 7, nb0 = (sub >> 2) * 64, n0 = (sub & 3) * 128;
  const int ldB = (r + 1) * 512;
  const unsigned short* Bp = Bcat + (size_t)262144 * (((r - 1) * (r + 2)) >> 1);
  const unsigned short* abase = src + (size_t)(s - r) * NH + (size_t)nb0 * HD;
  const float* bet = beta + (size_t)(r - 1) * 512;
  const int nk = (r + 1) * 8;
  const int lane = tid & 63, wave = tid >> 6, wm = wave >> 1, wn = wave & 1;
  const int r_ = tid >> 3, kc = (tid & 7) * 8;

  floatx4 acc[2][4] = {};
  uint4 ra[2], rb4[4];
  ra[0] = *(const uint4*)(abase + (size_t)r_ * HD + kc);
  ra[1] = *(const uint4*)(abase + (size_t)(r_ + 32) * HD + kc);
#pragma unroll
  for (int p = 0; p < 4; ++p)
    rb4[p] = *(const uint4*)(Bp + (size_t)(n0 + r_ + p * 32) * ldB + kc);

  for (int k = 0; k < nk; ++k) {
    __syncthreads();
    *(uint4*)&As[r_ * LDA + kc] = ra[0];
    *(uint4*)&As[(r_ + 32) * LDA + kc] = ra[1];
#pragma unroll
    for (int p = 0; p < 4; ++p)
      *(uint4*)&Bs[(r_ + p * 32) * LDA + kc] = rb4[p];
    __syncthreads();
    if (k + 1 < nk) {
      int kcol = (k + 1) * 64, q = kcol >> 9, acol = kcol & 511;
      const unsigned short* a0 = abase + (size_t)q * NH + acol;
      ra[0] = *(const uint4*)(a0 + (size_t)r_ * HD + kc);
      ra[1] = *(const uint4*)(a0 + (size_t)(r_ + 32) * HD + kc);
#pragma unroll
      for (int p = 0; p < 4; ++p)
        rb4[p] = *(const uint4*)(Bp + (size_t)(n0 + r_ + p * 32) * ldB + kcol + kc);
    }
    gemm_core24(As, Bs, acc, wm, wn, lane);
  }

  const bool wdst = (bid < mainWG);
  const bool wout = (!wdst) || (s == L_prev + m);
  unsigned short* d1 = dst + (size_t)s * NH + (size_t)nb0 * HD;
  unsigned short* d2 = outs + (size_t)s * NH + (size_t)nb0 * HD;
  const int rb = lane & 15, rg = (lane >> 4) * 4;
#pragma unroll
  for (int i = 0; i < 2; ++i)
#pragma unroll
    for (int jj = 0; jj < 4; ++jj) {
      int col = n0 + wn * 64 + jj * 16 + rb;
      float bv = bet[col];
#pragma unroll
      for (int reg = 0; reg < 4; ++reg) {
        int row = wm * 32 + i * 16 + rg + reg;
        unsigned short v = f2b(acc[i][jj][reg] + bv);
        if (wdst) d1[(size_t)row * HD + col] = v;
        if (wout) d2[(size_t)row * HD + col] = v;
      }
    }
}

// ---- phase 3: Y = outs_flat @ W_out^T + b_out  (fp32 out) ----
__global__ __launch_bounds__(256) void k_gemm_out(const unsigned short* __restrict__ outs,
                                                  const unsigned short* __restrict__ Wb,
                                                  const float* __restrict__ bias,
                                                  float* __restrict__ Y) {
  __shared__ unsigned short As[64 * LDA];
  __shared__ unsigned short Bs[128 * LDA];
  int tid = threadIdx.x;
  int mtile = blockIdx.x >> 2, ntile = blockIdx.x & 3;
  int m0 = mtile * 64, n0 = ntile * 128;
  int lane = tid & 63, wave = tid >> 6, wm = wave >> 1, wn = wave & 1;
  floatx4 acc[2][4] = {};
  for (int k0 = 0; k0 < 512; k0 += 64) {
    stageA_bf16(As, outs + (size_t)m0 * 512 + k0, tid);
    stageB(Bs, Wb + (size_t)n0 * 512 + k0, 512, tid);
    __syncthreads();
    gemm_core24(As, Bs, acc, wm, wn, lane);
    __syncthreads();
  }
  int rb = lane & 15, rg = (lane >> 4) * 4;
#pragma unroll
  for (int i = 0; i < 2; ++i)
#pragma unroll
    for (int j = 0; j < 4; ++j) {
      int col = n0 + wn * 64 + j * 16 + rb;
      float bv = bias[col];
#pragma unroll
      for (int reg = 0; reg < 4; ++reg) {
        int row = m0 + wm * 32 + i * 16 + rg + reg;
        Y[(size_t)row * 512 + col] = acc[i][j][reg] + bv;
      }
    }
}

// ---- weights fp32 -> bf16: W_in -> Win_b, W_sani -> Bcat_1 (layout [W1|W2] as-is), W_out -> Wout_b ----
__global__ __launch_bounds__(256) void k_cvtw(const float* __restrict__ Win,
                                              const float* __restrict__ Wsani,
                                              const float* __restrict__ Wout,
                                              unsigned short* __restrict__ dWin,
                                              unsigned short* __restrict__ dBcat1,
                                              unsigned short* __restrict__ dWout) {
  int i = blockIdx.x * 256 + threadIdx.x;  // float4 index, total 262144
  const float* src;
  unsigned short* dst;
  int off;
  if (i < 65536)       { src = Win;   dst = dWin;   off = i; }
  else if (i < 196608) { src = Wsani; dst = dBcat1; off = i - 65536; }
  else                 { src = Wout;  dst = dWout;  off = i - 196608; }
  floatx4 v = *(const floatx4*)(src + (size_t)off * 4);
  uint2 u;
  u.x = (unsigned)f2b(v.x) | ((unsigned)f2b(v.y) << 16);
  u.y = (unsigned)f2b(v.z) | ((unsigned)f2b(v.w) << 16);
  *(uint2*)(dst + (size_t)off * 4) = u;
}

__global__ void k_copy(const uint4* __restrict__ src, uint4* __restrict__ dst, int n) {
  int i = blockIdx.x * blockDim.x + threadIdx.x;
  if (i < n) dst[i] = src[i];
}

// ---- loss: per n, column-softmax over 64 consecutive Y rows, dot with emb ----
__global__ __launch_bounds__(256) void k_loss(const float* __restrict__ Y,
                                              const float* __restrict__ table,
                                              const int* __restrict__ labels,
                                              float* __restrict__ partials) {
  int n = blockIdx.x, tid = threadIdx.x;
  float total = 0.f;
#pragma unroll
  for (int e2 = 0; e2 < 2; ++e2) {
    int e = e2 * 256 + tid;
    float mx = -1e30f;
    for (int l = 0; l < 64; ++l)
      mx = fmaxf(mx, Y[(size_t)(n * 64 + l) * 512 + e]);
    float se = 0.f;
    for (int l = 0; l < 64; ++l)
      se += expf(Y[(size_t)(n * 64 + l) * 512 + e] - mx);
    float lse = mx + logf(se);
    for (int l = 0; l < 64; ++l) {
      float embv = table[(size_t)labels[n * 64 + l] * ED + e];
      total += embv * (Y[(size_t)(n * 64 + l) * 512 + e] - lse);
    }
  }
  __shared__ float red[256];
  red[tid] = total;
  __syncthreads();
  for (int s2 = 128; s2 > 0; s2 >>= 1) {
    if (tid < s2) red[tid] += red[tid + s2];
    __syncthreads();
  }
  if (tid == 0) partials[n] = red[0];
}

__global__ void k_final(const float* __restrict__ partials, float* __restrict__ out) {
  if (threadIdx.x == 0) {
    double s = 0.0;
    for (int i = 0; i < 128; ++i) s += (double)partials[i];
    out[0] = (float)(-s / 65536.0);
  }
}

extern "C" void kernel_launch(void* const* d_in, const int* in_sizes, int n_in,
                              void* d_out, int out_size, void* d_ws, size_t ws_size,
                              hipStream_t stream) {
  const int*   labels = (const int*)d_in[0];
  const float* table  = (const float*)d_in[1];
  const float* W_in   = (const float*)d_in[2];
  const float* b_in   = (const float*)d_in[3];
  const float* W_sani = (const float*)d_in[4];
  const float* b_sani = (const float*)d_in[5];
  const float* W_out  = (const float*)d_in[6];
  const float* b_out  = (const float*)d_in[7];

  char* ws = (char*)d_ws;
  unsigned short* Win_b  = (unsigned short*)(ws + OFF_WIN);
  unsigned short* Wout_b = (unsigned short*)(ws + OFF_WOUT);
  unsigned short* xt     = (unsigned short*)(ws + OFF_XT);
  unsigned short* lvl0   = (unsigned short*)(ws + OFF_LVL0);
  unsigned short* lvl1   = (unsigned short*)(ws + OFF_LVL1);
  unsigned short* outs   = (unsigned short*)(ws + OFF_OUTS);
  float*          Pa     = (float*)(ws + OFF_PA);
  float*          Pb     = (float*)(ws + OFF_PB);
  unsigned short* Bcat   = (unsigned short*)(ws + OFF_BCAT);
  float*          beta   = (float*)(ws + OFF_BETA);
  float*          parts  = (float*)(ws + OFF_PART);
  float*          Y      = (float*)(ws + OFF_Y);

  // weights -> bf16 (Bcat_1 = bf16(W_sani) directly: layout [W1|W2] matches segment order)
  k_cvtw<<<1024, 256, 0, stream>>>(W_in, W_sani, W_out, Win_b, Bcat, Wout_b);
  k_gemm_emb<<<512, 256, 0, stream>>>(table, labels, Win_b, b_in, xt);
  k_copy<<<32, 256, 0, stream>>>((const uint4*)xt, (uint4*)outs, 8192);   // outs[0] = x_t[0]

  // bias chain beta_1..beta_4
  k_copy<<<1, 128, 0, stream>>>((const uint4*)b_sani, (uint4*)beta, 128);
  k_bias_step<<<512, 64, 0, stream>>>(W_sani, b_sani, beta,        beta + 512);
  k_bias_step<<<512, 64, 0, stream>>>(W_sani, b_sani, beta + 512,  beta + 1024);
  k_bias_step<<<512, 64, 0, stream>>>(W_sani, b_sani, beta + 1024, beta + 1536);

  // coefficient chain: P1 -> P2 -> P3 -> P4 (f32, hi/lo split GEMMs); Bcat_r via transpose
  k_trW <<<128, 256, 0, stream>>>(W_sani, Pa);                 // P1 (2 mats)
  k_coef<<< 96, 256, 0, stream>>>(Pa, Pb, W_sani, 1);          // P2 (3 mats)
  k_trB <<<192, 256, 0, stream>>>(Pb, Bcat + 524288, 2);
  k_coef<<<128, 256, 0, stream>>>(Pb, Pa, W_sani, 2);          // P3 (4 mats)
  k_trB <<<256, 256, 0, stream>>>(Pa, Bcat + 1310720, 3);
  k_coef<<<160, 256, 0, stream>>>(Pa, Pb, W_sani, 3);          // P4 (5 mats)
  k_trB <<<320, 256, 0, stream>>>(Pb, Bcat + 2359296, 4);

  // 16 multi-level steps (15 x m=4, 1 x m=3)
  const unsigned short* srcp = xt;
  for (int j = 1; j <= 16; ++j) {
    int L_prev = 4 * (j - 1);
    int m = (j == 16) ? 3 : 4;
    int nmain = 64 - (L_prev + m);
    unsigned short* dstp = ((j - 1) & 1) ? lvl1 : lvl0;
    k_step<<<(nmain + m - 1) * 8, 256, 0, stream>>>(srcp, dstp, outs, Bcat, beta,
                                                    L_prev, m, nmain);
    srcp = dstp;
  }

  k_gemm_out<<<512, 256, 0, stream>>>(outs, Wout_b, b_out, Y);
  k_loss<<<128, 256, 0, stream>>>(Y, table, labels, parts);
  k_final<<<1, 64, 0, stream>>>(parts, (float*)d_out);
}